// Round 9
// baseline (8199.403 us; speedup 1.0000x reference)
//
#include <hip/hip_runtime.h>
#include <stdint.h>

#define SEQ 2048
#define HID 2048
#define INP 2048
#define NTH 4        // theta+1
#define K3  (HID*3)  // 6144: split-bf16 K-tripling

typedef uint32_t u32x4  __attribute__((ext_vector_type(4)));
typedef short    short8 __attribute__((ext_vector_type(8)));
typedef float    f32x4  __attribute__((ext_vector_type(4)));
typedef uint32_t uint4v __attribute__((ext_vector_type(4)));

// ---------------------------------------------------------------------------
// wave64 all-VALU DPP sum (unchanged)
// ---------------------------------------------------------------------------
template<int CTRL>
__device__ __forceinline__ float dpp_add(float x) {
    int y = __builtin_amdgcn_update_dpp(0, __float_as_int(x), CTRL, 0xF, 0xF, true);
    return x + __int_as_float(y);
}
__device__ __forceinline__ float wave_sum64(float x) {
    x = dpp_add<0x111>(x); x = dpp_add<0x112>(x); x = dpp_add<0x114>(x);
    x = dpp_add<0x118>(x); x = dpp_add<0x142>(x); x = dpp_add<0x143>(x);
    return x;  // lane 63 holds total
}

// ---------------------------------------------------------------------------
// Split-bf16 conversion (unchanged from R6)
// ---------------------------------------------------------------------------
__device__ __forceinline__ ushort bf16h(float x) {
    uint32_t u = __float_as_uint(x);
    return (ushort)((u + 0x7fffu + ((u >> 16) & 1u)) >> 16);   // RNE
}
template<int BSIDE>
__global__ __launch_bounds__(256)
void convert3_k(const float* __restrict__ X, ushort* __restrict__ X3) {
    const size_t t = (size_t)blockIdx.x * 256 + threadIdx.x;
    float xs[8];
    *reinterpret_cast<float4*>(&xs[0]) = *reinterpret_cast<const float4*>(X + t * 8);
    *reinterpret_cast<float4*>(&xs[4]) = *reinterpret_cast<const float4*>(X + t * 8 + 4);
    ushort o[24];
#pragma unroll
    for (int i = 0; i < 8; ++i) {
        const ushort hi = bf16h(xs[i]);
        const float hif = __uint_as_float(((uint32_t)hi) << 16);
        const ushort lo = bf16h(xs[i] - hif);
        o[i * 3 + 0] = hi;
        o[i * 3 + 1] = BSIDE ? lo : hi;
        o[i * 3 + 2] = BSIDE ? hi : lo;
    }
    ushort* pd = X3 + t * 24;
#pragma unroll
    for (int v = 0; v < 3; ++v)
        *reinterpret_cast<uint4v*>(pd + v * 8) = *reinterpret_cast<const uint4v*>(&o[v * 8]);
}

// ---------------------------------------------------------------------------
// MFMA GEMM (unchanged from R6)
// ---------------------------------------------------------------------------
template<int RELU>
__global__ __launch_bounds__(256, 2)
void mfma_gemm(const ushort* __restrict__ A3, const ushort* __restrict__ B3,
               const float* __restrict__ D, const float* __restrict__ bias,
               float* __restrict__ C) {
    __shared__ ushort sA[128 * 64];
    __shared__ ushort sB[64 * 64];
    const int tid = threadIdx.x;
    const int w = tid >> 6, lane = tid & 63;
    const int m0 = blockIdx.y * 128, n0 = blockIdx.x * 64;

    f32x4 acc[2][4];
#pragma unroll
    for (int m = 0; m < 2; ++m)
#pragma unroll
        for (int n = 0; n < 4; ++n) acc[m][n] = (f32x4)0.f;

    const int c16s = (lane & 7) ^ ((lane >> 3) & 7);

    for (int kt = 0; kt < K3; kt += 64) {
#pragma unroll
        for (int i = 0; i < 4; ++i) {
            const int c = w * 4 + i;
            const int row = c * 8 + (lane >> 3);
            const ushort* src = A3 + (size_t)(m0 + row) * K3 + kt + c16s * 8;
            __builtin_amdgcn_global_load_lds(
                (const __attribute__((address_space(1))) uint32_t*)src,
                (__attribute__((address_space(3))) uint32_t*)(sA + c * 512), 16, 0, 0);
        }
#pragma unroll
        for (int i = 0; i < 2; ++i) {
            const int c = w * 2 + i;
            const int row = c * 8 + (lane >> 3);
            const ushort* src = B3 + (size_t)(n0 + row) * K3 + kt + c16s * 8;
            __builtin_amdgcn_global_load_lds(
                (const __attribute__((address_space(1))) uint32_t*)src,
                (__attribute__((address_space(3))) uint32_t*)(sB + c * 512), 16, 0, 0);
        }
        __syncthreads();

#pragma unroll
        for (int ks = 0; ks < 2; ++ks) {
            short8 af[2], bf[4];
#pragma unroll
            for (int m = 0; m < 2; ++m) {
                const int row = w * 32 + m * 16 + (lane & 15);
                const int c16 = (ks * 4 + (lane >> 4)) ^ (row & 7);
                af[m] = *reinterpret_cast<const short8*>(sA + row * 64 + c16 * 8);
            }
#pragma unroll
            for (int n = 0; n < 4; ++n) {
                const int row = n * 16 + (lane & 15);
                const int c16 = (ks * 4 + (lane >> 4)) ^ (row & 7);
                bf[n] = *reinterpret_cast<const short8*>(sB + row * 64 + c16 * 8);
            }
#pragma unroll
            for (int m = 0; m < 2; ++m)
#pragma unroll
                for (int n = 0; n < 4; ++n)
                    acc[m][n] = __builtin_amdgcn_mfma_f32_16x16x32_bf16(
                        af[m], bf[n], acc[m][n], 0, 0, 0);
        }
        __syncthreads();
    }

#pragma unroll
    for (int m = 0; m < 2; ++m)
#pragma unroll
        for (int n = 0; n < 4; ++n) {
            const int col = n0 + n * 16 + (lane & 15);
            const float bz = bias[col];
#pragma unroll
            for (int r = 0; r < 4; ++r) {
                const int rowm = m0 + w * 32 + m * 16 + (lane >> 4) * 4 + r;
                float v = acc[m][n][r] + D[(size_t)rowm * HID + col] + bz;
                if (RELU) v = fmaxf(v, 0.f);
                C[(size_t)rowm * HID + col] = v;
            }
        }
}

// ---------------------------------------------------------------------------
__global__ void init_state_k(const float* __restrict__ state,
                             unsigned long long* __restrict__ slots) {
    const int i = blockIdx.x * 256 + threadIdx.x;
    slots[i] = (unsigned long long)__float_as_uint(state[i]);
}

// ---------------------------------------------------------------------------
// Phase B scan, R7: wave-owned rows, ONE barrier/step.
// 64 WGs x 512 thr (8 waves). Wave w owns rows base+4w..+3 over FULL k:
// 128 weight VGPRs/lane (2 waves/SIMD -> 256-VGPR budget OK), 8 ds_read_b128
// + 128 FMA per lane per step, DPP-reduce, lane 63 relu+publishes directly.
// No k-split => no part[] buffer, no S2 barrier, no finalizer phase.
// hl double-buffered => single barrier S1/step is safe: a wave writes
// hl[(t+1)&1] only after passing S1(t) .. and can only REACH its next write
// of hl[t&1] (step t+2 staging) after passing S1(t+1), whose arrival-count
// pairing requires every wave to have arrived at S1(t+1), i.e. finished its
// step-t reads of hl[t&1]. Slot protocol (tagged 8B, 4-rotation, coherent
// polls) unchanged; wave-granularity induction: publishing s+1 requires
// detecting all rows at s, which transitively requires every wave past s-3.
// ---------------------------------------------------------------------------
__global__ __launch_bounds__(512, 1)
void rnn_scan(const float* __restrict__ Whh, float* __restrict__ out0,
              unsigned long long* __restrict__ slots, float* __restrict__ tail) {
    __shared__ float hl[2][HID];
    const int tid  = threadIdx.x;
    const int lane = tid & 63;
    const int w    = tid >> 6;            // 0..7
    const int base = blockIdx.x * 32;     // first row of this WG
    const int kb   = lane * 4;            // k base; + j*256, j=0..7

    // Persistent weights: wrow[rr][j] = Whh[base+4w+rr][kb + j*256 .. +3]
    float4 wrow[4][8];
#pragma unroll
    for (int rr = 0; rr < 4; ++rr)
#pragma unroll
        for (int j = 0; j < 8; ++j)
            wrow[rr][j] = *reinterpret_cast<const float4*>(
                &Whh[(size_t)(base + 4 * w + rr) * HID + kb + j * 256]);

    for (int t = 0; t < SEQ; ++t) {
        // lane 63: pre0[t] for this wave's 4 rows — issued before the poll.
        float4 pre4 = make_float4(0.f, 0.f, 0.f, 0.f);
        if (lane == 63)
            pre4 = *reinterpret_cast<const float4*>(&out0[(size_t)t * HID + base + 4 * w]);

        // Poll this thread's 4 tagged pairs (two coherent dwordx4, one RTT).
        const unsigned long long* sp =
            slots + (size_t)(t & 3) * HID + (size_t)tid * 4;
        const uint32_t tag = (uint32_t)t;
        u32x4 q0, q1;
        for (;;) {
            asm volatile(
                "global_load_dwordx4 %0, %2, off sc0 sc1\n\t"
                "global_load_dwordx4 %1, %2, off offset:16 sc0 sc1\n\t"
                "s_waitcnt vmcnt(0)"
                : "=&v"(q0), "=&v"(q1) : "v"(sp) : "memory");
            if (q0.y == tag && q0.w == tag && q1.y == tag && q1.w == tag) break;
            __builtin_amdgcn_s_sleep(1);
        }
        *reinterpret_cast<float4*>(&hl[t & 1][tid * 4]) =
            make_float4(__uint_as_float(q0.x), __uint_as_float(q0.z),
                        __uint_as_float(q1.x), __uint_as_float(q1.z));
        __syncthreads();                                   // S1 (only barrier)

        // 8 x ds_read_b128, each float4 reused across this wave's 4 rows.
        const float* hb = hl[t & 1];
        float acc0 = 0.f, acc1 = 0.f, acc2 = 0.f, acc3 = 0.f;
#pragma unroll
        for (int j = 0; j < 8; ++j) {
            const float4 hv = *reinterpret_cast<const float4*>(&hb[kb + j * 256]);
            acc0 = fmaf(wrow[0][j].x, hv.x, acc0); acc0 = fmaf(wrow[0][j].y, hv.y, acc0);
            acc0 = fmaf(wrow[0][j].z, hv.z, acc0); acc0 = fmaf(wrow[0][j].w, hv.w, acc0);
            acc1 = fmaf(wrow[1][j].x, hv.x, acc1); acc1 = fmaf(wrow[1][j].y, hv.y, acc1);
            acc1 = fmaf(wrow[1][j].z, hv.z, acc1); acc1 = fmaf(wrow[1][j].w, hv.w, acc1);
            acc2 = fmaf(wrow[2][j].x, hv.x, acc2); acc2 = fmaf(wrow[2][j].y, hv.y, acc2);
            acc2 = fmaf(wrow[2][j].z, hv.z, acc2); acc2 = fmaf(wrow[2][j].w, hv.w, acc2);
            acc3 = fmaf(wrow[3][j].x, hv.x, acc3); acc3 = fmaf(wrow[3][j].y, hv.y, acc3);
            acc3 = fmaf(wrow[3][j].z, hv.z, acc3); acc3 = fmaf(wrow[3][j].w, hv.w, acc3);
        }
        acc0 = wave_sum64(acc0); acc1 = wave_sum64(acc1);
        acc2 = wave_sum64(acc2); acc3 = wave_sum64(acc3);

        if (lane == 63) {
            const float h0 = fmaxf(acc0 + pre4.x, 0.f);
            const float h1 = fmaxf(acc1 + pre4.y, 0.f);
            const float h2 = fmaxf(acc2 + pre4.z, 0.f);
            const float h3 = fmaxf(acc3 + pre4.w, 0.f);
            const int grow = base + 4 * w;
            *reinterpret_cast<float4*>(&out0[(size_t)t * HID + grow]) =
                make_float4(h0, h1, h2, h3);               // outputs[0][t]
            unsigned long long* ps = slots + (size_t)((t + 1) & 3) * HID + grow;
            const unsigned long long tg = (unsigned long long)(uint32_t)(t + 1) << 32;
            __hip_atomic_store(ps + 0, tg | __float_as_uint(h0),
                               __ATOMIC_RELAXED, __HIP_MEMORY_SCOPE_AGENT);
            __hip_atomic_store(ps + 1, tg | __float_as_uint(h1),
                               __ATOMIC_RELAXED, __HIP_MEMORY_SCOPE_AGENT);
            __hip_atomic_store(ps + 2, tg | __float_as_uint(h2),
                               __ATOMIC_RELAXED, __HIP_MEMORY_SCOPE_AGENT);
            __hip_atomic_store(ps + 3, tg | __float_as_uint(h3),
                               __ATOMIC_RELAXED, __HIP_MEMORY_SCOPE_AGENT);
            if (t == SEQ - 1)
                *reinterpret_cast<float4*>(&tail[grow]) = make_float4(h0, h1, h2, h3);
        }
    }
}

// ---------------------------------------------------------------------------
extern "C" void kernel_launch(void* const* d_in, const int* in_sizes, int n_in,
                              void* d_out, int out_size, void* d_ws, size_t ws_size,
                              hipStream_t stream) {
    const float* input    = (const float*)d_in[0];
    const float* internal = (const float*)d_in[1];
    const float* state    = (const float*)d_in[2];
    const float* wih      = (const float*)d_in[3];
    const float* whh      = (const float*)d_in[4];
    const float* bias     = (const float*)d_in[5];

    float* out = (float*)d_out;
    unsigned long long* slots = (unsigned long long*)d_ws;   // 64KB
    const size_t SH = (size_t)SEQ * HID;
    const size_t CVT = (size_t)HID * K3 * sizeof(ushort);    // 24MB per matrix
    const size_t need = 65536 + 3 * CVT;                     // ~72MB

    const dim3 cgrid((HID * INP / 8) / 256);
    if (ws_size >= need) {
        ushort* B3whh = (ushort*)((char*)d_ws + 65536);
        ushort* B3wih = (ushort*)((char*)d_ws + 65536 + CVT);
        ushort* A3    = (ushort*)((char*)d_ws + 65536 + 2 * CVT);

        convert3_k<1><<<cgrid, 256, 0, stream>>>(wih, B3wih);
        convert3_k<0><<<cgrid, 256, 0, stream>>>(input, A3);
        mfma_gemm<0><<<dim3(HID / 64, SEQ / 128), 256, 0, stream>>>(
            A3, B3wih, internal, bias, out);
        convert3_k<1><<<cgrid, 256, 0, stream>>>(whh, B3whh);
        init_state_k<<<8, 256, 0, stream>>>(state, slots);
        rnn_scan<<<64, 512, 0, stream>>>(whh, out, slots, out + (size_t)NTH * SH);
        for (int th = 1; th < NTH; ++th) {
            convert3_k<0><<<cgrid, 256, 0, stream>>>(out + (size_t)(th - 1) * SH, A3);
            mfma_gemm<1><<<dim3(HID / 64, SEQ / 128), 256, 0, stream>>>(
                A3, B3whh, internal + (size_t)th * SH, bias, out + (size_t)th * SH);
        }
    } else {
        // defensive, never taken in this harness (ws_size >= need)
        init_state_k<<<8, 256, 0, stream>>>(state, slots);
        rnn_scan<<<64, 512, 0, stream>>>(whh, out, slots, out + (size_t)NTH * SH);
    }
}